// Round 1
// baseline (241.759 us; speedup 1.0000x reference)
//
#include <hip/hip_runtime.h>
#include <hip/hip_bf16.h>
#include <math.h>

#define ROWS 256
#define DD 64
#define EE 8
#define HH 64
#define GH 32

typedef __attribute__((ext_vector_type(8))) short bf16x8;
typedef __attribute__((ext_vector_type(4))) float f32x4;

static __device__ __forceinline__ short f2bf(float f) {
    unsigned u = __builtin_bit_cast(unsigned, f);
    unsigned r = (u + 0x7fffu + ((u >> 16) & 1u)) >> 16;  // round-to-nearest-even
    return (short)r;
}

__global__ __launch_bounds__(256, 2) void moe_kernel(
    const float* __restrict__ A, const float* __restrict__ S,
    const float* __restrict__ gw1, const float* __restrict__ gb1,
    const float* __restrict__ gw2, const float* __restrict__ gb2,
    const float* __restrict__ ew1, const float* __restrict__ eb1,
    const float* __restrict__ ew2, const float* __restrict__ eb2,
    float* __restrict__ out)
{
    // xs row stride 72 shorts = 144B = 9*16B: 16B-aligned frags, 2-way bank alias (free)
    __shared__ short xs[ROWS][72];
    __shared__ float ps[ROWS][EE];
    __shared__ float rowsum[ROWS];

    const int t = threadIdx.x;
    const int row0 = blockIdx.x * ROWS;
    const int lane = t & 63;
    const int wave = t >> 6;
    const int quad = lane >> 4;
    const int lr = lane & 15;

    rowsum[t] = 0.0f;

    // ---- Phase 1: per-thread gating + x -> LDS (bf16) ----
    {
        const int row = row0 + t;
        const float* arow = A + (size_t)row * 32;
        const float* srow = S + (size_t)row * 32;
        float s[32];
        #pragma unroll
        for (int i = 0; i < 8; ++i) {
            float4 v = ((const float4*)arow)[i];
            short4 b; b.x = f2bf(v.x); b.y = f2bf(v.y); b.z = f2bf(v.z); b.w = f2bf(v.w);
            *(short4*)&xs[t][i * 4] = b;
        }
        #pragma unroll
        for (int i = 0; i < 8; ++i) {
            float4 v = ((const float4*)srow)[i];
            s[i*4+0] = v.x; s[i*4+1] = v.y; s[i*4+2] = v.z; s[i*4+3] = v.w;
            short4 b; b.x = f2bf(v.x); b.y = f2bf(v.y); b.z = f2bf(v.z); b.w = f2bf(v.w);
            *(short4*)&xs[t][32 + i * 4] = b;
        }
        float hacc[GH];
        #pragma unroll
        for (int g = 0; g < GH; ++g) hacc[g] = gb1[g];
        #pragma unroll
        for (int d = 0; d < 32; ++d) {
            float sv = s[d];
            #pragma unroll
            for (int g = 0; g < GH; ++g) hacc[g] = fmaf(sv, gw1[d * GH + g], hacc[g]);
        }
        float lg[EE];
        #pragma unroll
        for (int e = 0; e < EE; ++e) lg[e] = gb2[e];
        #pragma unroll
        for (int g = 0; g < GH; ++g) {
            float hv = fmaxf(hacc[g], 0.0f);
            #pragma unroll
            for (int e = 0; e < EE; ++e) lg[e] = fmaf(hv, gw2[g * EE + e], lg[e]);
        }
        float mx = lg[0];
        #pragma unroll
        for (int e = 1; e < EE; ++e) mx = fmaxf(mx, lg[e]);
        float sum = 0.f, pv[EE];
        #pragma unroll
        for (int e = 0; e < EE; ++e) { pv[e] = expf(lg[e] - mx); sum += pv[e]; }
        float inv = 1.0f / sum;
        #pragma unroll
        for (int e = 0; e < EE; ++e) ps[t][e] = pv[e] * inv;
    }

    // ---- Load B fragments (W1 columns) + per-column w2/b1 into registers ----
    // wave owns columns n in [wave*128, wave*128+128) = experts {2w, 2w+1}
    bf16x8 blo[8], bhi[8];
    float w2p[8], b1c[8];
    const int e0 = wave * 2;
    #pragma unroll
    for (int tt = 0; tt < 8; ++tt) {
        int n = wave * 128 + tt * 16 + lr;
        int e = n >> 6, h = n & 63;
        w2p[tt] = ew2[e * HH + h];
        b1c[tt] = eb1[e * HH + h];
        #pragma unroll
        for (int j = 0; j < 8; ++j) {
            int dl = quad * 8 + j;                       // k for lo frag
            blo[tt][j] = f2bf(ew1[((e * DD + dl) * HH) + h]);
            bhi[tt][j] = f2bf(ew1[((e * DD + dl + 32) * HH) + h]);
        }
    }

    __syncthreads();

    // ---- Phase 2: MFMA over 16-row tiles ----
    #pragma unroll 1
    for (int rt = 0; rt < ROWS / 16; ++rt) {
        const short* xp = &xs[rt * 16 + lr][quad * 8];
        bf16x8 alo = *(const bf16x8*)xp;          // A[m=lr][k=quad*8+j], k in [0,32)
        bf16x8 ahi = *(const bf16x8*)(xp + 32);   // k in [32,64)
        f32x4 acc[8];
        #pragma unroll
        for (int tt = 0; tt < 8; ++tt) acc[tt] = (f32x4){0.f, 0.f, 0.f, 0.f};
        #pragma unroll
        for (int tt = 0; tt < 8; ++tt)
            acc[tt] = __builtin_amdgcn_mfma_f32_16x16x32_bf16(alo, blo[tt], acc[tt], 0, 0, 0);
        #pragma unroll
        for (int tt = 0; tt < 8; ++tt)
            acc[tt] = __builtin_amdgcn_mfma_f32_16x16x32_bf16(ahi, bhi[tt], acc[tt], 0, 0, 0);

        // epilogue: bias+relu, fold w2, per-expert partials (4 tiles each)
        float pe0[4] = {0, 0, 0, 0}, pe1[4] = {0, 0, 0, 0};
        #pragma unroll
        for (int tt = 0; tt < 8; ++tt) {
            #pragma unroll
            for (int r = 0; r < 4; ++r) {
                float v = fmaxf(acc[tt][r] + b1c[tt], 0.0f);
                if (tt < 4) pe0[r] = fmaf(v, w2p[tt], pe0[r]);
                else        pe1[r] = fmaf(v, w2p[tt], pe1[r]);
            }
        }
        #pragma unroll
        for (int r = 0; r < 4; ++r) {
            int rw = rt * 16 + quad * 4 + r;      // C/D row = quad*4+reg
            float c = pe0[r] * ps[rw][e0] + pe1[r] * ps[rw][e0 + 1];
            c += __shfl_xor(c, 1);
            c += __shfl_xor(c, 2);
            c += __shfl_xor(c, 4);
            c += __shfl_xor(c, 8);
            if (lr == 0) atomicAdd(&rowsum[rw], c);
        }
    }

    __syncthreads();
    {
        float extra = 0.f;
        #pragma unroll
        for (int e = 0; e < EE; ++e) extra = fmaf(ps[t][e], eb2[e], extra);
        out[row0 + t] = rowsum[t] + extra;
    }
}

extern "C" void kernel_launch(void* const* d_in, const int* in_sizes, int n_in,
                              void* d_out, int out_size, void* d_ws, size_t ws_size,
                              hipStream_t stream) {
    const float* A   = (const float*)d_in[0];
    const float* S   = (const float*)d_in[1];
    const float* gw1 = (const float*)d_in[2];
    const float* gb1 = (const float*)d_in[3];
    const float* gw2 = (const float*)d_in[4];
    const float* gb2 = (const float*)d_in[5];
    const float* ew1 = (const float*)d_in[6];
    const float* eb1 = (const float*)d_in[7];
    const float* ew2 = (const float*)d_in[8];
    const float* eb2 = (const float*)d_in[9];
    float* out = (float*)d_out;

    const int B = in_sizes[0] / 32;
    dim3 grid(B / ROWS), block(256);
    hipLaunchKernelGGL(moe_kernel, grid, block, 0, stream,
                       A, S, gw1, gb1, gw2, gb2, ew1, eb1, ew2, eb2, out);
}

// Round 3
// 193.965 us; speedup vs baseline: 1.2464x; 1.2464x over previous
//
#include <hip/hip_runtime.h>
#include <hip/hip_bf16.h>
#include <math.h>

#define ROWS 256
#define DD 64
#define EE 8
#define HH 64
#define GH 32

typedef __attribute__((ext_vector_type(8))) short bf16x8;
typedef __attribute__((ext_vector_type(4))) float f32x4;

static __device__ __forceinline__ short f2bf(float f) {
    unsigned u = __builtin_bit_cast(unsigned, f);
    unsigned r = (u + 0x7fffu + ((u >> 16) & 1u)) >> 16;  // round-to-nearest-even
    return (short)r;
}
static __device__ __forceinline__ float bf2f(unsigned short b) {
    unsigned u = ((unsigned)b) << 16;
    return __builtin_bit_cast(float, u);
}
// butterfly add via DPP (ctrl must be a compile-time constant)
template <int CTRL>
static __device__ __forceinline__ float dpp_add(float x) {
    int xi = __builtin_bit_cast(int, x);
    int yi = __builtin_amdgcn_update_dpp(0, xi, CTRL, 0xF, 0xF, true);
    return x + __builtin_bit_cast(float, yi);
}

// Precompute W1 as bf16 MFMA B-fragments in d_ws.
// layout: frag index idx = wave<<10 | tt<<7 | half<<6 | lane, 8 shorts each (64 KB)
__global__ __launch_bounds__(256) void prep_kernel(const float* __restrict__ ew1,
                                                   short* __restrict__ wf) {
    int idx = blockIdx.x * 256 + threadIdx.x;   // 4096 frags
    int lane = idx & 63;
    int half = (idx >> 6) & 1;
    int tt   = (idx >> 7) & 7;
    int wave = (idx >> 10) & 3;
    int n = wave * 128 + tt * 16 + (lane & 15);
    int e = n >> 6, h = n & 63;
    int quad = lane >> 4;
    short v[8];
    #pragma unroll
    for (int j = 0; j < 8; ++j) {
        int dl = quad * 8 + j + half * 32;
        v[j] = f2bf(ew1[(e * DD + dl) * HH + h]);
    }
    *(bf16x8*)(wf + (size_t)idx * 8) = *(const bf16x8*)v;
}

__global__ __launch_bounds__(256, 4) void moe_kernel(
    const float* __restrict__ A, const float* __restrict__ S,
    const float* __restrict__ gw1, const float* __restrict__ gb1,
    const float* __restrict__ gw2, const float* __restrict__ gb2,
    const short* __restrict__ wf,  const float* __restrict__ eb1,
    const float* __restrict__ ew2, const float* __restrict__ eb2,
    float* __restrict__ out)
{
    // xs row = 72 shorts (144 B): [0..63] bf16 x-data, [64..65] = rowsum (f32), rest pad.
    // stride 144 B = 36 words -> rows shift 1 chunk/row -> conflict-free frag reads.
    __shared__ short xs[ROWS][72];                 // 36864 B
    __shared__ unsigned short psb[ROWS][EE];       // 4096 B  (bf16 gating probs)
    // total 40960 B -> 4 blocks/CU

    const int t = threadIdx.x;
    const int row0 = blockIdx.x * ROWS;
    const int lane = t & 63;
    const int wave = t >> 6;
    const int quad = lane >> 4;
    const int lr = lane & 15;

    float extra;  // per-thread bias term for its own row, lives across phases

    // ---- Phase 1: per-thread gating + x -> LDS (bf16) ----
    {
        const int row = row0 + t;
        const float* arow = A + (size_t)row * 32;
        const float* srow = S + (size_t)row * 32;
        float s[32];
        #pragma unroll
        for (int i = 0; i < 4; ++i) {
            float4 v0 = ((const float4*)arow)[2 * i];
            float4 v1 = ((const float4*)arow)[2 * i + 1];
            short v8[8] = { f2bf(v0.x), f2bf(v0.y), f2bf(v0.z), f2bf(v0.w),
                            f2bf(v1.x), f2bf(v1.y), f2bf(v1.z), f2bf(v1.w) };
            *(bf16x8*)&xs[t][i * 8] = *(const bf16x8*)v8;
        }
        #pragma unroll
        for (int i = 0; i < 4; ++i) {
            float4 v0 = ((const float4*)srow)[2 * i];
            float4 v1 = ((const float4*)srow)[2 * i + 1];
            s[i*8+0] = v0.x; s[i*8+1] = v0.y; s[i*8+2] = v0.z; s[i*8+3] = v0.w;
            s[i*8+4] = v1.x; s[i*8+5] = v1.y; s[i*8+6] = v1.z; s[i*8+7] = v1.w;
            short v8[8] = { f2bf(v0.x), f2bf(v0.y), f2bf(v0.z), f2bf(v0.w),
                            f2bf(v1.x), f2bf(v1.y), f2bf(v1.z), f2bf(v1.w) };
            *(bf16x8*)&xs[t][32 + i * 8] = *(const bf16x8*)v8;
        }
        *(float*)&xs[t][64] = 0.0f;   // rowsum init (lives in the row pad)

        float hacc[GH];
        #pragma unroll
        for (int g = 0; g < GH; ++g) hacc[g] = gb1[g];
        #pragma unroll
        for (int d = 0; d < 32; ++d) {
            float sv = s[d];
            #pragma unroll
            for (int g = 0; g < GH; ++g) hacc[g] = fmaf(sv, gw1[d * GH + g], hacc[g]);
        }
        float lg[EE];
        #pragma unroll
        for (int e = 0; e < EE; ++e) lg[e] = gb2[e];
        #pragma unroll
        for (int g = 0; g < GH; ++g) {
            float hv = fmaxf(hacc[g], 0.0f);
            #pragma unroll
            for (int e = 0; e < EE; ++e) lg[e] = fmaf(hv, gw2[g * EE + e], lg[e]);
        }
        float mx = lg[0];
        #pragma unroll
        for (int e = 1; e < EE; ++e) mx = fmaxf(mx, lg[e]);
        float sum = 0.f, pv[EE];
        #pragma unroll
        for (int e = 0; e < EE; ++e) { pv[e] = expf(lg[e] - mx); sum += pv[e]; }
        float inv = 1.0f / sum;
        unsigned short pb[EE];
        extra = 0.f;
        #pragma unroll
        for (int e = 0; e < EE; ++e) {
            float p = pv[e] * inv;
            extra = fmaf(p, eb2[e], extra);
            pb[e] = (unsigned short)f2bf(p);
        }
        *(bf16x8*)&psb[t][0] = *(const bf16x8*)pb;
    }

    // ---- Load B fragments (precomputed bf16) + per-column w2/b1 ----
    bf16x8 blo[8], bhi[8];
    float w2p[8], b1c[8];
    const int e0 = wave * 2;
    #pragma unroll
    for (int tt = 0; tt < 8; ++tt) {
        const short* base = wf + ((size_t)((wave * 8 + tt) * 128) + lane) * 8;
        blo[tt] = *(const bf16x8*)base;
        bhi[tt] = *(const bf16x8*)(base + 512);
        int n = wave * 128 + tt * 16 + lr;
        int e = n >> 6, h = n & 63;
        w2p[tt] = ew2[e * HH + h];
        b1c[tt] = eb1[e * HH + h];
    }

    __syncthreads();

    // ---- Phase 2: MFMA over 16-row tiles ----
    #pragma unroll 1
    for (int rt = 0; rt < ROWS / 16; ++rt) {
        const short* xp = &xs[rt * 16 + lr][quad * 8];
        bf16x8 alo = *(const bf16x8*)xp;          // A[m=lr][k=quad*8+j], k in [0,32)
        bf16x8 ahi = *(const bf16x8*)(xp + 32);   // k in [32,64)
        f32x4 acc[8];
        #pragma unroll
        for (int tt = 0; tt < 8; ++tt) acc[tt] = (f32x4){0.f, 0.f, 0.f, 0.f};
        #pragma unroll
        for (int tt = 0; tt < 8; ++tt)
            acc[tt] = __builtin_amdgcn_mfma_f32_16x16x32_bf16(alo, blo[tt], acc[tt], 0, 0, 0);
        #pragma unroll
        for (int tt = 0; tt < 8; ++tt)
            acc[tt] = __builtin_amdgcn_mfma_f32_16x16x32_bf16(ahi, bhi[tt], acc[tt], 0, 0, 0);

        // epilogue: bias+relu, fold w2, per-expert partials (4 tiles each)
        float pe0[4] = {0, 0, 0, 0}, pe1[4] = {0, 0, 0, 0};
        #pragma unroll
        for (int tt = 0; tt < 8; ++tt) {
            #pragma unroll
            for (int r = 0; r < 4; ++r) {
                float v = fmaxf(acc[tt][r] + b1c[tt], 0.0f);
                if (tt < 4) pe0[r] = fmaf(v, w2p[tt], pe0[r]);
                else        pe1[r] = fmaf(v, w2p[tt], pe1[r]);
            }
        }
        #pragma unroll
        for (int r = 0; r < 4; ++r) {
            int rw = rt * 16 + quad * 4 + r;      // C/D row = quad*4+reg
            float c = pe0[r] * bf2f(psb[rw][e0]) + pe1[r] * bf2f(psb[rw][e0 + 1]);
            // butterfly over the 16 lanes of this quad-row group (DPP, VALU pipe)
            c = dpp_add<0xB1>(c);                 // quad_perm [1,0,3,2]  (xor 1)
            c = dpp_add<0x4E>(c);                 // quad_perm [2,3,0,1]  (xor 2)
            c = dpp_add<0x124>(c);                // row_ror:4
            c = dpp_add<0x128>(c);                // row_ror:8
            if (lr == 0) atomicAdd((float*)&xs[rw][64], c);
        }
    }

    __syncthreads();
    out[row0 + t] = *(const float*)&xs[t][64] + extra;
}

extern "C" void kernel_launch(void* const* d_in, const int* in_sizes, int n_in,
                              void* d_out, int out_size, void* d_ws, size_t ws_size,
                              hipStream_t stream) {
    const float* A   = (const float*)d_in[0];
    const float* S   = (const float*)d_in[1];
    const float* gw1 = (const float*)d_in[2];
    const float* gb1 = (const float*)d_in[3];
    const float* gw2 = (const float*)d_in[4];
    const float* gb2 = (const float*)d_in[5];
    const float* ew1 = (const float*)d_in[6];
    const float* eb1 = (const float*)d_in[7];
    const float* ew2 = (const float*)d_in[8];
    const float* eb2 = (const float*)d_in[9];
    float* out = (float*)d_out;
    short* wf = (short*)d_ws;   // 64 KB of bf16 W1 fragments

    const int B = in_sizes[0] / 32;
    hipLaunchKernelGGL(prep_kernel, dim3(16), dim3(256), 0, stream, ew1, wf);
    hipLaunchKernelGGL(moe_kernel, dim3(B / ROWS), dim3(256), 0, stream,
                       A, S, gw1, gb1, gw2, gb2, wf, eb1, ew2, eb2, out);
}